// Round 9
// baseline (233.007 us; speedup 1.0000x reference)
//
#include <hip/hip_runtime.h>
#include <math.h>

namespace {
constexpr int kNB = 16;
constexpr int kNA = 1024;
constexpr int kP  = 65536;             // pairs per batch
constexpr int kNW = 8;
constexpr int kGA = 32;                // atoms per group
constexpr int kNG = kNA / kGA;         // 32 groups per batch
constexpr int kS  = 2;                 // pair-stream halves
constexpr int kHalfP = kP / kS;        // 32768
constexpr int kTileP = 4096;           // pairs per tile
constexpr int kTiles = kHalfP / kTileP;// 8
constexpr int kPPT = 8;                // pairs per thread per sub-chunk
constexpr int kQCap = 24;              // queue capacity (lambda=4/atom/tile)
constexpr int kQStr = 25;              // float4 stride -> conflict-free drain
constexpr int kAW = kNB * kNA * kNW;   // 131072 (atom,w) slots
constexpr float kInvCut = 1.0f / 6.0f;
constexpr float kPi = 3.14159265358979323846f;
}

// R7's proven fused structure, re-gridded: block = (batch b, 32-atom group g,
// stream half h). 256 threads = 32 atoms x 8 channels, 13 f32 register
// accumulators each. Grid 1024 -> 4 blocks/CU resident (R7 was grid-limited
// to 1). Scans its half of the batch's i0 stream (int4, coalesced, XCD-pinned
// L2 reuse); accepted pairs (~1/32) get batched gathers + f32 geometry,
// enqueued via integer LDS atomics; barrier; register drain. Partials out.
__global__ __launch_bounds__(256) void meam_partial(
    const float* __restrict__ coords,   // [NB*NA*3]
    const int*   __restrict__ aidx,     // [NB*2*P]
    const float* __restrict__ shifts,   // [NB*P*3]
    const int*   __restrict__ species,  // [NB*NA]
    const float* __restrict__ rs,       // [4*8]
    const float* __restrict__ inta,     // [4*8]
    float* __restrict__ part)           // [kS*13*kAW]
{
  __shared__ int    qcnt[kGA];
  __shared__ float4 qpay[kGA * kQStr];  // 12.8 KB

  // blockIdx = ((g*kS)+h)*16 + b  ->  blockIdx%8 == b%8 (XCD-pinned per batch)
  const int b  = blockIdx.x & 15;
  const int r  = blockIdx.x >> 4;       // 0..63
  const int h  = r & (kS - 1);
  const int g  = r >> 1;                // 0..31
  const int lo = g * kGA;
  const int tid = threadIdx.x;
  const int a   = tid >> 3;             // local atom 0..31
  const int w   = tid & 7;              // wave channel

  const int   s     = species[b * kNA + lo + a];
  const float rsw   = rs[s * kNW + w];
  const float intaw = inta[s * kNW + w];

  const int*   i0base = aidx + (size_t)(b * 2 + 0) * kP;
  const int*   i1base = aidx + (size_t)(b * 2 + 1) * kP;
  const float* sbase  = shifts + (size_t)b * kP * 3;
  const float* cbase  = coords + (size_t)b * kNA * 3;

  if (tid < kGA) qcnt[tid] = 0;

  float a0=0.f,a1=0.f,a2=0.f,a3=0.f,a4=0.f,a5=0.f,a6=0.f;
  float a7=0.f,a8=0.f,a9=0.f,a10=0.f,a11=0.f,a12=0.f;

  __syncthreads();

  const int hbase = h * kHalfP;
  for (int t = 0; t < kTiles; ++t) {
    // ---- bin: two sub-chunks of 8 pairs/thread (keeps staging regs small)
#pragma unroll
    for (int c = 0; c < 2; ++c) {
      const int p0 = hbase + t * kTileP + c * (kTileP / 2) + tid * kPPT;
      const int4 c0 = *(const int4*)(i0base + p0);
      const int4 c1 = *(const int4*)(i0base + p0 + 4);
      int ids[kPPT] = {c0.x, c0.y, c0.z, c0.w, c1.x, c1.y, c1.z, c1.w};

      unsigned am = 0;
      int j1v[kPPT];
#pragma unroll
      for (int k = 0; k < kPPT; ++k) {
        const int la = ids[k] - lo;
        if ((unsigned)la < (unsigned)kGA) { am |= 1u << k; j1v[k] = i1base[p0 + k]; }
      }
      float cjx[kPPT], cjy[kPPT], cjz[kPPT];
      float cix[kPPT], ciy[kPPT], ciz[kPPT];
      float shx[kPPT], shy[kPPT], shz[kPPT];
#pragma unroll
      for (int k = 0; k < kPPT; ++k) {
        if (am & (1u << k)) {
          const int jj = j1v[k], ii = ids[k], p = p0 + k;
          cjx[k] = cbase[jj * 3 + 0]; cjy[k] = cbase[jj * 3 + 1]; cjz[k] = cbase[jj * 3 + 2];
          cix[k] = cbase[ii * 3 + 0]; ciy[k] = cbase[ii * 3 + 1]; ciz[k] = cbase[ii * 3 + 2];
          shx[k] = sbase[p * 3 + 0];  shy[k] = sbase[p * 3 + 1];  shz[k] = sbase[p * 3 + 2];
        }
      }
#pragma unroll
      for (int k = 0; k < kPPT; ++k) {
        if (am & (1u << k)) {
          const bool valid = (shx[k] > -1.0e9f) & (shy[k] > -1.0e9f) & (shz[k] > -1.0e9f);
          const float dx = cix[k] - cjx[k] + shx[k];
          const float dy = ciy[k] - cjy[k] + shy[k];
          const float dz = ciz[k] - cjz[k] + shz[k];
          const float dist = sqrtf(dx * dx + dy * dy + dz * dz);
          const float rr = dist * kInvCut;
          float f = 0.5f * (__cosf(kPi * fminf(rr, 1.0f)) + 1.0f);
          if (!valid | (rr >= 1.0f)) f = 0.0f;
          if (f != 0.0f) {
            const int la = ids[k] - lo;
            const int slot = atomicAdd(&qcnt[la], 1);   // ds_add_rtn (int)
            if (slot < kQCap) qpay[la * kQStr + slot] = make_float4(dx, dy, dz, f);
          }
        }
      }
    }
    __syncthreads();

    // ---- drain: 8 channel-threads of atom a (same wave) read its queue ----
    const int n = min(qcnt[a], kQCap);
    for (int j = 0; j < n; ++j) {
      const float4 q = qpay[a * kQStr + j];             // LDS broadcast x8
      const float dist = sqrtf(q.x * q.x + q.y * q.y + q.z * q.z);
      const float inv = (dist > 1e-12f) ? (1.0f / dist) : 1.0f;
      const float ux = q.x * inv, uy = q.y * inv, uz = q.z * inv;
      const float dr = dist - rsw;
      const float rad = __expf(-intaw * dr * dr);
      const float fr = q.w * rad;
      a0 += fr;
      const float rx = fr * ux, ry = fr * uy, rz = fr * uz;
      a1 += rx;        a2 += ry;        a3 += rz;
      a4 += rx * ux;   a5 += rx * uy;   a6 += rx * uz;
      a7 += ry * ux;   a8 += ry * uy;   a9 += ry * uz;
      a10 += rz * ux;  a11 += rz * uy;  a12 += rz * uz;
    }
    if (w == 0) qcnt[a] = 0;      // same wave as the n-read: program order safe
    __syncthreads();
  }

  // ---- write 13 partials; tid-consecutive idx -> coalesced stores ----
  const int idx = (b * kNA + lo + a) * kNW + w;
  const float av[13] = {a0,a1,a2,a3,a4,a5,a6,a7,a8,a9,a10,a11,a12};
#pragma unroll
  for (int k = 0; k < 13; ++k)
    part[(size_t)(h * 13 + k) * kAW + idx] = av[k];
}

// Combine the kS partials, square, group, scale. One thread per (atom, w).
__global__ __launch_bounds__(256) void reduce_out(
    const float* __restrict__ part,     // [kS*13*kAW]
    const int*   __restrict__ species,  // [NB*NA]
    const float* __restrict__ params,   // [4]
    float* __restrict__ out)            // [NB*NA*24]
{
  const int t = blockIdx.x * 256 + threadIdx.x;   // 0..131071
  float v[13];
#pragma unroll
  for (int k = 0; k < 13; ++k)
    v[k] = part[(size_t)k * kAW + t] + part[(size_t)(13 + k) * kAW + t];

  const int atom = t >> 3;
  const int w = t & 7;
  const float pm = params[atom >= 0 ? species[atom] : 0];

  const float o0 = v[0] * v[0];
  const float o1 = v[1]*v[1] + v[2]*v[2] + v[3]*v[3];
  const float o2 = v[4]*v[4] + v[5]*v[5] + v[6]*v[6] + v[7]*v[7] +
                   v[8]*v[8] + v[9]*v[9] + v[10]*v[10] + v[11]*v[11] +
                   v[12]*v[12];

  float* o = out + (size_t)atom * 24;
  o[0 * kNW + w] = pm * o0;
  o[1 * kNW + w] = pm * o1;
  o[2 * kNW + w] = pm * o2;
}

extern "C" void kernel_launch(void* const* d_in, const int* in_sizes, int n_in,
                              void* d_out, int out_size, void* d_ws, size_t ws_size,
                              hipStream_t stream) {
  const float* coords  = (const float*)d_in[0];  // (16,1024,3)
  const int*   aidx    = (const int*)d_in[2];    // (16,2,65536)
  const float* shifts  = (const float*)d_in[3];  // (16,65536,3)
  const int*   species = (const int*)d_in[4];    // (16384,)
  const float* rs      = (const float*)d_in[5];  // (4,8)
  const float* inta    = (const float*)d_in[6];  // (4,8)
  const float* params  = (const float*)d_in[7];  // (4,)
  float* out = (float*)d_out;                    // (16384, 24)

  float* part = (float*)d_ws;                    // 2*13*131072 f32 = 13.6 MB

  meam_partial<<<kNB * kNG * kS, 256, 0, stream>>>(
      coords, aidx, shifts, species, rs, inta, part);
  reduce_out<<<kAW / 256, 256, 0, stream>>>(part, species, params, out);
}